// Round 17
// baseline (274.884 us; speedup 1.0000x reference)
//
#include <hip/hip_runtime.h>
#include <math.h>

// Problem constants (fixed by setup_inputs)
#define B   16
#define L   512
#define H   768
#define HV4 192      // H/4 float4s per row
#define S1  32
#define S2  128
#define NS  8
#define M   4
#define CH  16       // L-chunk rows per partial block
#define NCHUNK 32    // L / CH

// ---------------------------------------------------------------------------
// K1 (fused): 1536 blocks, 384 threads. [R13-identical]
// ---------------------------------------------------------------------------
__global__ __launch_bounds__(384)
void k_pool(const float* __restrict__ e1, const float* __restrict__ e2,
            const int* __restrict__ am,
            const float* __restrict__ s1, const float* __restrict__ s2,
            const int* __restrict__ iam,
            const float* __restrict__ hs, const int* __restrict__ st_,
            const int* __restrict__ en_,
            float* __restrict__ row_cls,
            float* __restrict__ sp_part, float* __restrict__ sp_cnt,
            float* __restrict__ sel_part, float* __restrict__ sel_cnt) {
  const int bid = blockIdx.x;
  const int t = threadIdx.x;
  const int half = t / 192;       // wave-uniform (waves 0-2 vs 3-5)
  const int tt = t % 192;
  __shared__ int   idxL[S2];
  __shared__ int   cntS;
  __shared__ float4 pf[192];      // half-1 partials for the combine

  if (bid < 512) {
    const int i = bid;
    if (t < 64) {
      const int m0 = am[i * S2 + t];
      const int m1 = am[i * S2 + 64 + t];
      const unsigned long long b0 = __ballot(m0 != 0);
      const unsigned long long b1 = __ballot(m1 != 0);
      const int c0 = (int)__popcll(b0);
      if (m0) idxL[(int)__popcll(b0 & ((1ULL << t) - 1))] = t;
      if (m1) idxL[c0 + (int)__popcll(b1 & ((1ULL << t) - 1))] = 64 + t;
      if (t == 0) cntS = c0 + (int)__popcll(b1);
    }
    __syncthreads();
    const int cnt = cntS;
    const int cntH = (cnt + 1 - half) >> 1;   // half0 ceil, half1 floor
    const float4* p1 = (const float4*)e1 + (size_t)i * (S2 * HV4) + tt;
    const float4* p2 = (const float4*)e2 + (size_t)i * (S2 * HV4) + tt;
    float ax = 0.f, ay = 0.f, az = 0.f, aw = 0.f;
    int kk = 0;
    for (; kk + 3 < cntH; kk += 4) {
      const int j0 = idxL[2 * kk + half];
      const int j1 = idxL[2 * (kk + 1) + half];
      const int j2 = idxL[2 * (kk + 2) + half];
      const int j3 = idxL[2 * (kk + 3) + half];
      float4 a0 = p1[j0 * HV4], b0 = p2[j0 * HV4];
      float4 a1 = p1[j1 * HV4], b1 = p2[j1 * HV4];
      float4 a2 = p1[j2 * HV4], b2 = p2[j2 * HV4];
      float4 a3 = p1[j3 * HV4], b3 = p2[j3 * HV4];
      ax += (a0.x + b0.x) + (a1.x + b1.x) + (a2.x + b2.x) + (a3.x + b3.x);
      ay += (a0.y + b0.y) + (a1.y + b1.y) + (a2.y + b2.y) + (a3.y + b3.y);
      az += (a0.z + b0.z) + (a1.z + b1.z) + (a2.z + b2.z) + (a3.z + b3.z);
      aw += (a0.w + b0.w) + (a1.w + b1.w) + (a2.w + b2.w) + (a3.w + b3.w);
    }
    for (; kk < cntH; ++kk) {
      const int j = idxL[2 * kk + half];
      float4 a = p1[j * HV4], b = p2[j * HV4];
      ax += a.x + b.x; ay += a.y + b.y; az += a.z + b.z; aw += a.w + b.w;
    }
    if (half == 1) { float4 o; o.x = ax; o.y = ay; o.z = az; o.w = aw; pf[tt] = o; }
    __syncthreads();
    if (half == 0) {
      const float inv = 1.f / (float)cnt;
      float4 o = pf[tt];
      o.x = (ax + o.x) * inv; o.y = (ay + o.y) * inv;
      o.z = (az + o.z) * inv; o.w = (aw + o.w) * inv;
      ((float4*)row_cls)[(size_t)i * HV4 + tt] = o;
    }
  } else if (bid < 1024) {
    const int blk = bid - 512;
    const int b = blk >> 5, c = blk & 31;
    if (t < 64) {
      const int m = (t < CH) ? iam[b * L + c * CH + t] : 0;
      const unsigned long long bm = __ballot(m != 0);
      if (m) idxL[(int)__popcll(bm & ((1ULL << t) - 1))] = t;
      if (t == 0) { const int cc = (int)__popcll(bm); cntS = cc; sp_cnt[blk] = (float)cc; }
    }
    __syncthreads();
    const int cnt = cntS;
    const int cntH = (cnt + 1 - half) >> 1;
    const float4* p1 = (const float4*)s1 + ((size_t)b * L + c * CH) * HV4 + tt;
    const float4* p2 = (const float4*)s2 + ((size_t)b * L + c * CH) * HV4 + tt;
    float ax = 0.f, ay = 0.f, az = 0.f, aw = 0.f;
    int kk = 0;
    for (; kk + 1 < cntH; kk += 2) {
      const int l0 = idxL[2 * kk + half];
      const int l1 = idxL[2 * (kk + 1) + half];
      float4 a0 = p1[l0 * HV4], b0 = p2[l0 * HV4];
      float4 a1 = p1[l1 * HV4], b1 = p2[l1 * HV4];
      ax += (a0.x + b0.x) + (a1.x + b1.x);
      ay += (a0.y + b0.y) + (a1.y + b1.y);
      az += (a0.z + b0.z) + (a1.z + b1.z);
      aw += (a0.w + b0.w) + (a1.w + b1.w);
    }
    for (; kk < cntH; ++kk) {
      const int l = idxL[2 * kk + half];
      float4 a = p1[l * HV4], b = p2[l * HV4];
      ax += a.x + b.x; ay += a.y + b.y; az += a.z + b.z; aw += a.w + b.w;
    }
    if (half == 1) { float4 o; o.x = ax; o.y = ay; o.z = az; o.w = aw; pf[tt] = o; }
    __syncthreads();
    if (half == 0) {
      float4 o = pf[tt];
      o.x += ax; o.y += ay; o.z += az; o.w += aw;
      ((float4*)sp_part)[(size_t)blk * HV4 + tt] = o;
    }
  } else {
    const int blk = bid - 1024;
    const int b = blk >> 5, c = blk & 31;
    const int st = st_[b], en = en_[b];
    const int lo = st > c * CH ? st : c * CH;
    const int hi = en < c * CH + CH ? en : c * CH + CH;
    const float4* p = (const float4*)hs + (size_t)b * L * HV4 + tt;
    float ax = 0.f, ay = 0.f, az = 0.f, aw = 0.f;
    for (int l = lo + half; l < hi; l += 2) {   // this half's rows, in-bounds
      float4 a0 = p[l * HV4];
      ax += a0.x; ay += a0.y; az += a0.z; aw += a0.w;
    }
    if (half == 1) { float4 o; o.x = ax; o.y = ay; o.z = az; o.w = aw; pf[tt] = o; }
    __syncthreads();
    if (half == 0) {
      float4 o = pf[tt];
      o.x += ax; o.y += ay; o.z += az; o.w += aw;
      ((float4*)sel_part)[(size_t)blk * HV4 + tt] = o;
      if (tt == 0) sel_cnt[blk] = (float)(hi > lo ? hi - lo : 0);
    }
  }
}

// ---------------------------------------------------------------------------
// K2: combines. Grid 32 blocks, 256 threads. [R13-identical]
// ---------------------------------------------------------------------------
__global__ __launch_bounds__(256)
void k_sp(const float* __restrict__ sp_part, const float* __restrict__ sp_cnt,
          const float* __restrict__ sel_part, const float* __restrict__ sel_cnt,
          const float* __restrict__ gamma_s, const float* __restrict__ beta_s,
          float* __restrict__ sp, float* __restrict__ sel_ln) {
  const int bid = blockIdx.x, t = threadIdx.x;
  const int lane = t & 63, w = t >> 6;
  __shared__ float red[8];
  if (bid < B) {
    const int b = bid;
    float csp = 0.f;
    for (int c = 0; c < NCHUNK; ++c) csp += sp_cnt[b * NCHUNK + c];
    const float inv = 1.f / csp;
    #pragma unroll
    for (int k = 0; k < 3; ++k) {
      const int h = t + k * 256;
      float a = 0.f;
      #pragma unroll
      for (int c = 0; c < NCHUNK; ++c)
        a += sp_part[((size_t)b * NCHUNK + c) * H + h];
      sp[(size_t)b * H + h] = a * inv;
    }
  } else {
    const int b = bid - B;
    float csel = 0.f;
    for (int c = 0; c < NCHUNK; ++c) csel += sel_cnt[b * NCHUNK + c];
    const float invc = 1.f / csel;
    float selv[3];
    #pragma unroll
    for (int k = 0; k < 3; ++k) {
      const int h = t + k * 256;
      float s = 0.f;
      #pragma unroll
      for (int c = 0; c < NCHUNK; ++c)
        s += sel_part[((size_t)b * NCHUNK + c) * H + h];
      selv[k] = s * invc;
    }
    float s = selv[0] + selv[1] + selv[2];
    float ss = selv[0] * selv[0] + selv[1] * selv[1] + selv[2] * selv[2];
    #pragma unroll
    for (int off = 32; off > 0; off >>= 1) {
      s += __shfl_down(s, off);
      ss += __shfl_down(ss, off);
    }
    if (lane == 0) { red[w] = s; red[4 + w] = ss; }
    __syncthreads();
    const float S = red[0] + red[1] + red[2] + red[3];
    const float SS = red[4] + red[5] + red[6] + red[7];
    const float mu = S / (float)H;
    const float var = SS / (float)H - mu * mu;
    const float rstd = rsqrtf(var + 1e-12f);
    #pragma unroll
    for (int k = 0; k < 3; ++k) {
      const int h = t + k * 256;
      sel_ln[(size_t)b * H + h] = (selv[k] - mu) * rstd * gamma_s[h] + beta_s[h];
    }
  }
}

// ---------------------------------------------------------------------------
// K3: q + sim partials, grid 12 (ht) x 1024.  R17: ALL 16 b's in-block, so
// each W_attn column tile is read by EXACTLY ONE block (2.25MB total demand,
// no XCD duplication).  Wave w = batch b (spL broadcast reads), lane = h.
// Then simp from the block's rc column slice (131KB, unique per block).
// ---------------------------------------------------------------------------
__global__ __launch_bounds__(1024)
void k_q(const float* __restrict__ sp, const float* __restrict__ W_attn,
         const float* __restrict__ rc, float* __restrict__ simp) {
  const int ht = blockIdx.x, t = threadIdx.x;
  const int lane = t & 63, w = t >> 6;   // 16 waves; wave = b
  __shared__ float spL[B * H];   // 49 KiB
  __shared__ float qL[B * 64];   // 4 KiB
  // stage sp (16x768), coalesced f4
  {
    float4* d4 = (float4*)spL;
    const float4* s4 = (const float4*)sp;
    #pragma unroll
    for (int k = 0; k < 3; ++k) d4[t + k * 1024] = s4[t + k * 1024];
  }
  __syncthreads();
  // q[b][hl]: full 768-dot per lane; W_attn reads identical across waves -> L1
  {
    const float* sv = spL + w * H;
    const float* wp = W_attn + ht * 64 + lane;
    float acc = 0.f;
    #pragma unroll 8
    for (int d = 0; d < H; ++d) acc += sv[d] * wp[(size_t)d * H];
    qL[w * 64 + lane] = acc;
  }
  __syncthreads();
  // simp: 512 rc rows, 16 rows/pass (wave = row within pass)
  #pragma unroll 1
  for (int pass = 0; pass < 32; ++pass) {
    const int row = pass * 16 + w;           // 0..511
    const int b = row >> 5, i = row & 31;
    float p = rc[(size_t)row * H + ht * 64 + lane] * qL[b * 64 + lane];
    p += __shfl_down(p, 32); p += __shfl_down(p, 16); p += __shfl_down(p, 8);
    p += __shfl_down(p, 4);  p += __shfl_down(p, 2);  p += __shfl_down(p, 1);
    if (lane == 0) simp[((size_t)b * 12 + ht) * S1 + i] = p;
  }
}

// ---------------------------------------------------------------------------
// K4: sims reduce + ragged softmax + pooled materialization.
// Grid 128 (b x n), 256 threads. rc demand = 4 rows/block = 1.5MB total.
// ---------------------------------------------------------------------------
__global__ __launch_bounds__(256)
void k_attn_pool(const float* __restrict__ simp, const float* __restrict__ rc,
                 const int* __restrict__ extra_index, float* __restrict__ pooled) {
  const int bid = blockIdx.x, t = threadIdx.x;
  const int b = bid >> 3, n = bid & 7;
  __shared__ float simL[M];
  __shared__ float wL[M];
  if (t < M) {
    float a = 0.f;
    #pragma unroll
    for (int ht = 0; ht < 12; ++ht)
      a += simp[((size_t)b * 12 + ht) * S1 + n * M + t];
    simL[t] = a;
  }
  __syncthreads();
  if (t == 0) {
    const int vid = extra_index[b * NS + n];
    const float scale = 0.036084391824351615f;  // 1/sqrt(768)
    float x[M], mx = -1e30f;
    #pragma unroll
    for (int m = 0; m < M; ++m) {
      x[m] = (m < vid) ? simL[m] * scale : -1e30f;
      mx = fmaxf(mx, x[m]);
    }
    float s = 0.f, e[M];
    #pragma unroll
    for (int m = 0; m < M; ++m) { e[m] = expf(x[m] - mx); s += e[m]; }
    #pragma unroll
    for (int m = 0; m < M; ++m) wL[m] = e[m] / s;
  }
  __syncthreads();
  const float w0 = wL[0], w1 = wL[1], w2 = wL[2], w3 = wL[3];
  const float* r0 = rc + (size_t)(b * S1 + n * M + 0) * H;
  const float* r1 = rc + (size_t)(b * S1 + n * M + 1) * H;
  const float* r2 = rc + (size_t)(b * S1 + n * M + 2) * H;
  const float* r3 = rc + (size_t)(b * S1 + n * M + 3) * H;
  #pragma unroll
  for (int k = 0; k < 3; ++k) {
    const int d = t + k * 256;
    pooled[(size_t)bid * H + d] = w0 * r0[d] + w1 * r1[d] + w2 * r2[d] + w3 * r3[d];
  }
}

// ---------------------------------------------------------------------------
// K5: y = pooled @ W_t^T + b_t.  Grid 12 (hc) x 1024.  R17: each W_t row is
// read by EXACTLY ONE block (2.25MB total).  W_t rows in registers (R16
// prefetch pattern); pooled streamed through LDS in 4 chunks of 32 pairs.
// ---------------------------------------------------------------------------
__global__ __launch_bounds__(1024)
void k_transform(const float* __restrict__ pooled, const float* __restrict__ W_t,
                 const float* __restrict__ b_t, float* __restrict__ yb) {
  const int hc = blockIdx.x, t = threadIdx.x;
  const int lane = t & 63, w = t >> 6;   // 16 waves, wave owns rows h=hc*64+w*4+r
  __shared__ float4 pooledL4[32 * HV4];  // 98 KiB: 32 pairs x 768 floats
  float4 wv[4][3];
  float bt[4];
  #pragma unroll
  for (int r = 0; r < 4; ++r) {
    const int h = hc * 64 + w * 4 + r;
    const float4* wr = (const float4*)(W_t + (size_t)h * H);
    wv[r][0] = wr[lane];
    wv[r][1] = wr[lane + 64];
    wv[r][2] = wr[lane + 128];
    bt[r] = b_t[h];
  }
  #pragma unroll 1
  for (int c = 0; c < 4; ++c) {
    const float4* src = (const float4*)pooled + (size_t)c * 32 * HV4;
    #pragma unroll
    for (int k = 0; k < 6; ++k) pooledL4[t + k * 1024] = src[t + k * 1024];
    __syncthreads();
    #pragma unroll 1
    for (int p = 0; p < 32; ++p) {
      const float4* pq = pooledL4 + p * HV4;
      const float4 p0 = pq[lane];
      const float4 p1 = pq[lane + 64];
      const float4 p2 = pq[lane + 128];
      float pr[4];
      #pragma unroll
      for (int r = 0; r < 4; ++r) {
        pr[r] = wv[r][0].x * p0.x + wv[r][0].y * p0.y + wv[r][0].z * p0.z + wv[r][0].w * p0.w
              + wv[r][1].x * p1.x + wv[r][1].y * p1.y + wv[r][1].z * p1.z + wv[r][1].w * p1.w
              + wv[r][2].x * p2.x + wv[r][2].y * p2.y + wv[r][2].z * p2.z + wv[r][2].w * p2.w;
      }
      #pragma unroll
      for (int off = 32; off > 0; off >>= 1) {
        #pragma unroll
        for (int r = 0; r < 4; ++r) pr[r] += __shfl_down(pr[r], off);
      }
      if (lane == 0) {
        const int gp = c * 32 + p;   // = b*8+n
        #pragma unroll
        for (int r = 0; r < 4; ++r)
          yb[(size_t)gp * H + hc * 64 + w * 4 + r] = pr[r] + bt[r];
      }
    }
    __syncthreads();
  }
}

// ---------------------------------------------------------------------------
// K6: fused row-LayerNorm + cosine score. [R13-identical]
// ---------------------------------------------------------------------------
__global__ __launch_bounds__(256)
void k_lnscore(const float* __restrict__ yb, const float* __restrict__ gamma,
               const float* __restrict__ beta, const float* __restrict__ sel_ln,
               float* __restrict__ out) {
  const int b = blockIdx.x, t = threadIdx.x;
  const int lane = t & 63, w = t >> 6;
  __shared__ float redS[NS * 4];
  __shared__ float redQ[NS * 4];
  float v[NS][3];
  for (int n = 0; n < NS; ++n) {
    float s = 0.f, ss = 0.f;
    #pragma unroll
    for (int k = 0; k < 3; ++k) {
      const float x = yb[((size_t)b * NS + n) * H + t + k * 256];
      v[n][k] = x; s += x; ss += x * x;
    }
    #pragma unroll
    for (int off = 32; off > 0; off >>= 1) {
      s += __shfl_down(s, off);
      ss += __shfl_down(ss, off);
    }
    if (lane == 0) { redS[n * 4 + w] = s; redQ[n * 4 + w] = ss; }
  }
  __syncthreads();
  float g[3], be[3];
  #pragma unroll
  for (int k = 0; k < 3; ++k) { g[k] = gamma[t + k * 256]; be[k] = beta[t + k * 256]; }
  float S[3] = {0.f, 0.f, 0.f}, SS[3] = {0.f, 0.f, 0.f};
  for (int n = 0; n < NS; ++n) {
    const float Sn = redS[n * 4] + redS[n * 4 + 1] + redS[n * 4 + 2] + redS[n * 4 + 3];
    const float Qn = redQ[n * 4] + redQ[n * 4 + 1] + redQ[n * 4 + 2] + redQ[n * 4 + 3];
    const float mu = Sn / (float)H;
    const float var = Qn / (float)H - mu * mu;
    const float rstd = rsqrtf(var + 1e-12f);
    #pragma unroll
    for (int k = 0; k < 3; ++k) {
      const float c = (v[n][k] - mu) * rstd * g[k] + be[k];
      S[k] += c; SS[k] += c * c;
    }
  }
  #pragma unroll
  for (int k = 0; k < 3; ++k) {
    const int h = t + k * 256;
    const float sl = sel_ln[(size_t)b * H + h];
    const float n1 = 2.8284271247461903f * fabsf(sl);  // sqrt(8)*|sel|
    const float n2 = sqrtf(SS[k]);
    out[(size_t)b * H + h] = sl * S[k] / (fmaxf(n1, 1e-8f) * fmaxf(n2, 1e-8f));
  }
}

// ---------------------------------------------------------------------------
extern "C" void kernel_launch(void* const* d_in, const int* in_sizes, int n_in,
                              void* d_out, int out_size, void* d_ws, size_t ws_size,
                              hipStream_t stream) {
  const float* hidden_states = (const float*)d_in[0];
  const float* sent_h1       = (const float*)d_in[1];
  const float* sent_h2       = (const float*)d_in[2];
  const int*   attention_mask= (const int*)  d_in[3];
  const float* expl_h1       = (const float*)d_in[4];
  const float* expl_h2       = (const float*)d_in[5];
  const int*   extra_am      = (const int*)  d_in[6];
  const int*   extra_index   = (const int*)  d_in[7];
  const int*   extra_start   = (const int*)  d_in[8];
  const int*   extra_end     = (const int*)  d_in[9];
  const float* W_attn        = (const float*)d_in[10];
  const float* W_t           = (const float*)d_in[11];
  const float* b_t           = (const float*)d_in[12];
  const float* gamma_t       = (const float*)d_in[13];
  const float* beta_t        = (const float*)d_in[14];
  const float* gamma_s       = (const float*)d_in[15];
  const float* beta_s        = (const float*)d_in[16];
  float* out = (float*)d_out;

  float* ws = (float*)d_ws;
  float* row_cls  = ws;                        // 512*768
  float* sp_part  = row_cls + 512 * H;         // 512*768
  float* sp_cnt   = sp_part + 512 * H;         // 512
  float* sel_part = sp_cnt + 512;              // 512*768
  float* sel_cnt  = sel_part + 512 * H;        // 512
  float* sel_ln   = sel_cnt + 512;             // 16*768
  float* sp       = sel_ln + B * H;            // 16*768
  float* simp     = sp + B * H;                // 16*12*32
  float* pooled   = simp + B * 12 * S1;        // 128*768
  float* yb       = pooled + B * NS * H;       // 128*768

  k_pool<<<1536, 384, 0, stream>>>(expl_h1, expl_h2, extra_am,
                                   sent_h1, sent_h2, attention_mask,
                                   hidden_states, extra_start, extra_end,
                                   row_cls, sp_part, sp_cnt, sel_part, sel_cnt);
  k_sp<<<32, 256, 0, stream>>>(sp_part, sp_cnt, sel_part, sel_cnt,
                               gamma_s, beta_s, sp, sel_ln);
  k_q<<<12, 1024, 0, stream>>>(sp, W_attn, row_cls, simp);
  k_attn_pool<<<128, 256, 0, stream>>>(simp, row_cls, extra_index, pooled);
  k_transform<<<12, 1024, 0, stream>>>(pooled, W_t, b_t, yb);
  k_lnscore<<<B, 256, 0, stream>>>(yb, gamma_t, beta_t, sel_ln, out);
}

// Round 18
// 80.447 us; speedup vs baseline: 3.4169x; 3.4169x over previous
//
#include <hip/hip_runtime.h>
#include <math.h>

// Problem constants (fixed by setup_inputs)
#define B   16
#define L   512
#define H   768
#define HV4 192      // H/4 float4s per row
#define S1  32
#define S2  128
#define NS  8
#define M   4
#define CH  16       // L-chunk rows per partial block
#define NCHUNK 32    // L / CH

// ---------------------------------------------------------------------------
// K1 (fused): 1536 blocks, 384 threads. [R13-identical]
// ---------------------------------------------------------------------------
__global__ __launch_bounds__(384)
void k_pool(const float* __restrict__ e1, const float* __restrict__ e2,
            const int* __restrict__ am,
            const float* __restrict__ s1, const float* __restrict__ s2,
            const int* __restrict__ iam,
            const float* __restrict__ hs, const int* __restrict__ st_,
            const int* __restrict__ en_,
            float* __restrict__ row_cls,
            float* __restrict__ sp_part, float* __restrict__ sp_cnt,
            float* __restrict__ sel_part, float* __restrict__ sel_cnt) {
  const int bid = blockIdx.x;
  const int t = threadIdx.x;
  const int half = t / 192;       // wave-uniform (waves 0-2 vs 3-5)
  const int tt = t % 192;
  __shared__ int   idxL[S2];
  __shared__ int   cntS;
  __shared__ float4 pf[192];      // half-1 partials for the combine

  if (bid < 512) {
    const int i = bid;
    if (t < 64) {
      const int m0 = am[i * S2 + t];
      const int m1 = am[i * S2 + 64 + t];
      const unsigned long long b0 = __ballot(m0 != 0);
      const unsigned long long b1 = __ballot(m1 != 0);
      const int c0 = (int)__popcll(b0);
      if (m0) idxL[(int)__popcll(b0 & ((1ULL << t) - 1))] = t;
      if (m1) idxL[c0 + (int)__popcll(b1 & ((1ULL << t) - 1))] = 64 + t;
      if (t == 0) cntS = c0 + (int)__popcll(b1);
    }
    __syncthreads();
    const int cnt = cntS;
    const int cntH = (cnt + 1 - half) >> 1;   // half0 ceil, half1 floor
    const float4* p1 = (const float4*)e1 + (size_t)i * (S2 * HV4) + tt;
    const float4* p2 = (const float4*)e2 + (size_t)i * (S2 * HV4) + tt;
    float ax = 0.f, ay = 0.f, az = 0.f, aw = 0.f;
    int kk = 0;
    for (; kk + 3 < cntH; kk += 4) {
      const int j0 = idxL[2 * kk + half];
      const int j1 = idxL[2 * (kk + 1) + half];
      const int j2 = idxL[2 * (kk + 2) + half];
      const int j3 = idxL[2 * (kk + 3) + half];
      float4 a0 = p1[j0 * HV4], b0 = p2[j0 * HV4];
      float4 a1 = p1[j1 * HV4], b1 = p2[j1 * HV4];
      float4 a2 = p1[j2 * HV4], b2 = p2[j2 * HV4];
      float4 a3 = p1[j3 * HV4], b3 = p2[j3 * HV4];
      ax += (a0.x + b0.x) + (a1.x + b1.x) + (a2.x + b2.x) + (a3.x + b3.x);
      ay += (a0.y + b0.y) + (a1.y + b1.y) + (a2.y + b2.y) + (a3.y + b3.y);
      az += (a0.z + b0.z) + (a1.z + b1.z) + (a2.z + b2.z) + (a3.z + b3.z);
      aw += (a0.w + b0.w) + (a1.w + b1.w) + (a2.w + b2.w) + (a3.w + b3.w);
    }
    for (; kk < cntH; ++kk) {
      const int j = idxL[2 * kk + half];
      float4 a = p1[j * HV4], b = p2[j * HV4];
      ax += a.x + b.x; ay += a.y + b.y; az += a.z + b.z; aw += a.w + b.w;
    }
    if (half == 1) { float4 o; o.x = ax; o.y = ay; o.z = az; o.w = aw; pf[tt] = o; }
    __syncthreads();
    if (half == 0) {
      const float inv = 1.f / (float)cnt;
      float4 o = pf[tt];
      o.x = (ax + o.x) * inv; o.y = (ay + o.y) * inv;
      o.z = (az + o.z) * inv; o.w = (aw + o.w) * inv;
      ((float4*)row_cls)[(size_t)i * HV4 + tt] = o;
    }
  } else if (bid < 1024) {
    const int blk = bid - 512;
    const int b = blk >> 5, c = blk & 31;
    if (t < 64) {
      const int m = (t < CH) ? iam[b * L + c * CH + t] : 0;
      const unsigned long long bm = __ballot(m != 0);
      if (m) idxL[(int)__popcll(bm & ((1ULL << t) - 1))] = t;
      if (t == 0) { const int cc = (int)__popcll(bm); cntS = cc; sp_cnt[blk] = (float)cc; }
    }
    __syncthreads();
    const int cnt = cntS;
    const int cntH = (cnt + 1 - half) >> 1;
    const float4* p1 = (const float4*)s1 + ((size_t)b * L + c * CH) * HV4 + tt;
    const float4* p2 = (const float4*)s2 + ((size_t)b * L + c * CH) * HV4 + tt;
    float ax = 0.f, ay = 0.f, az = 0.f, aw = 0.f;
    int kk = 0;
    for (; kk + 1 < cntH; kk += 2) {
      const int l0 = idxL[2 * kk + half];
      const int l1 = idxL[2 * (kk + 1) + half];
      float4 a0 = p1[l0 * HV4], b0 = p2[l0 * HV4];
      float4 a1 = p1[l1 * HV4], b1 = p2[l1 * HV4];
      ax += (a0.x + b0.x) + (a1.x + b1.x);
      ay += (a0.y + b0.y) + (a1.y + b1.y);
      az += (a0.z + b0.z) + (a1.z + b1.z);
      aw += (a0.w + b0.w) + (a1.w + b1.w);
    }
    for (; kk < cntH; ++kk) {
      const int l = idxL[2 * kk + half];
      float4 a = p1[l * HV4], b = p2[l * HV4];
      ax += a.x + b.x; ay += a.y + b.y; az += a.z + b.z; aw += a.w + b.w;
    }
    if (half == 1) { float4 o; o.x = ax; o.y = ay; o.z = az; o.w = aw; pf[tt] = o; }
    __syncthreads();
    if (half == 0) {
      float4 o = pf[tt];
      o.x += ax; o.y += ay; o.z += az; o.w += aw;
      ((float4*)sp_part)[(size_t)blk * HV4 + tt] = o;
    }
  } else {
    const int blk = bid - 1024;
    const int b = blk >> 5, c = blk & 31;
    const int st = st_[b], en = en_[b];
    const int lo = st > c * CH ? st : c * CH;
    const int hi = en < c * CH + CH ? en : c * CH + CH;
    const float4* p = (const float4*)hs + (size_t)b * L * HV4 + tt;
    float ax = 0.f, ay = 0.f, az = 0.f, aw = 0.f;
    for (int l = lo + half; l < hi; l += 2) {   // this half's rows, in-bounds
      float4 a0 = p[l * HV4];
      ax += a0.x; ay += a0.y; az += a0.z; aw += a0.w;
    }
    if (half == 1) { float4 o; o.x = ax; o.y = ay; o.z = az; o.w = aw; pf[tt] = o; }
    __syncthreads();
    if (half == 0) {
      float4 o = pf[tt];
      o.x += ax; o.y += ay; o.z += az; o.w += aw;
      ((float4*)sel_part)[(size_t)blk * HV4 + tt] = o;
      if (tt == 0) sel_cnt[blk] = (float)(hi > lo ? hi - lo : 0);
    }
  }
}

// ---------------------------------------------------------------------------
// K2: combines. Grid 32 blocks, 256 threads. [R13-identical]
// ---------------------------------------------------------------------------
__global__ __launch_bounds__(256)
void k_sp(const float* __restrict__ sp_part, const float* __restrict__ sp_cnt,
          const float* __restrict__ sel_part, const float* __restrict__ sel_cnt,
          const float* __restrict__ gamma_s, const float* __restrict__ beta_s,
          float* __restrict__ sp, float* __restrict__ sel_ln) {
  const int bid = blockIdx.x, t = threadIdx.x;
  const int lane = t & 63, w = t >> 6;
  __shared__ float red[8];
  if (bid < B) {
    const int b = bid;
    float csp = 0.f;
    for (int c = 0; c < NCHUNK; ++c) csp += sp_cnt[b * NCHUNK + c];
    const float inv = 1.f / csp;
    #pragma unroll
    for (int k = 0; k < 3; ++k) {
      const int h = t + k * 256;
      float a = 0.f;
      #pragma unroll
      for (int c = 0; c < NCHUNK; ++c)
        a += sp_part[((size_t)b * NCHUNK + c) * H + h];
      sp[(size_t)b * H + h] = a * inv;
    }
  } else {
    const int b = bid - B;
    float csel = 0.f;
    for (int c = 0; c < NCHUNK; ++c) csel += sel_cnt[b * NCHUNK + c];
    const float invc = 1.f / csel;
    float selv[3];
    #pragma unroll
    for (int k = 0; k < 3; ++k) {
      const int h = t + k * 256;
      float s = 0.f;
      #pragma unroll
      for (int c = 0; c < NCHUNK; ++c)
        s += sel_part[((size_t)b * NCHUNK + c) * H + h];
      selv[k] = s * invc;
    }
    float s = selv[0] + selv[1] + selv[2];
    float ss = selv[0] * selv[0] + selv[1] * selv[1] + selv[2] * selv[2];
    #pragma unroll
    for (int off = 32; off > 0; off >>= 1) {
      s += __shfl_down(s, off);
      ss += __shfl_down(ss, off);
    }
    if (lane == 0) { red[w] = s; red[4 + w] = ss; }
    __syncthreads();
    const float S = red[0] + red[1] + red[2] + red[3];
    const float SS = red[4] + red[5] + red[6] + red[7];
    const float mu = S / (float)H;
    const float var = SS / (float)H - mu * mu;
    const float rstd = rsqrtf(var + 1e-12f);
    #pragma unroll
    for (int k = 0; k < 3; ++k) {
      const int h = t + k * 256;
      sel_ln[(size_t)b * H + h] = (selv[k] - mu) * rstd * gamma_s[h] + beta_s[h];
    }
  }
}

// ---------------------------------------------------------------------------
// K3: q-tile + sim partials, 1024 threads. [R13-identical]
// ---------------------------------------------------------------------------
__global__ __launch_bounds__(1024)
void k_mid_q(const float* __restrict__ sp, const float* __restrict__ W_attn,
             const float* __restrict__ rc, float* __restrict__ simp) {
  const int bid = blockIdx.x, t = threadIdx.x;
  const int b = bid / 12, ht = bid % 12;
  const int lane = t & 63, w = t >> 6;     // 16 waves
  __shared__ float spL[H];
  __shared__ float red[1024];
  __shared__ float qt[64];
  if (t < H) spL[t] = sp[(size_t)b * H + t];
  __syncthreads();
  {
    const int h = ht * 64 + lane;
    const float* wp = W_attn + (size_t)(w * 48) * H + h;
    const float* sv = spL + w * 48;
    float acc = 0.f;
    #pragma unroll 8
    for (int i = 0; i < 48; ++i) acc += sv[i] * wp[(size_t)i * H];
    red[t] = acc;
  }
  __syncthreads();
  if (t < 64) {
    float a = 0.f;
    #pragma unroll
    for (int ww = 0; ww < 16; ++ww) a += red[ww * 64 + t];
    qt[t] = a;
  }
  __syncthreads();
  {
    const int i = t >> 5, sub = t & 31;
    const float* rr = rc + (size_t)(b * S1 + i) * H + ht * 64 + sub * 2;
    float p = qt[sub * 2] * rr[0] + qt[sub * 2 + 1] * rr[1];
    p += __shfl_down(p, 16);
    p += __shfl_down(p, 8);
    p += __shfl_down(p, 4);
    p += __shfl_down(p, 2);
    p += __shfl_down(p, 1);
    if (sub == 0) simp[((size_t)b * 12 + ht) * S1 + i] = p;
  }
}

// ---------------------------------------------------------------------------
// K4: sims reduce + ragged softmax + pooled materialization.
// Grid 128 (b x n), 256 threads. Each rc row read exactly once globally.
// [R17 body — verified correct there]
// ---------------------------------------------------------------------------
__global__ __launch_bounds__(256)
void k_attn_pool(const float* __restrict__ simp, const float* __restrict__ rc,
                 const int* __restrict__ extra_index, float* __restrict__ pooled) {
  const int bid = blockIdx.x, t = threadIdx.x;
  const int b = bid >> 3, n = bid & 7;
  __shared__ float simL[M];
  __shared__ float wL[M];
  if (t < M) {
    float a = 0.f;
    #pragma unroll
    for (int ht = 0; ht < 12; ++ht)
      a += simp[((size_t)b * 12 + ht) * S1 + n * M + t];
    simL[t] = a;
  }
  __syncthreads();
  if (t == 0) {
    const int vid = extra_index[b * NS + n];
    const float scale = 0.036084391824351615f;  // 1/sqrt(768)
    float x[M], mx = -1e30f;
    #pragma unroll
    for (int m = 0; m < M; ++m) {
      x[m] = (m < vid) ? simL[m] * scale : -1e30f;
      mx = fmaxf(mx, x[m]);
    }
    float s = 0.f, e[M];
    #pragma unroll
    for (int m = 0; m < M; ++m) { e[m] = expf(x[m] - mx); s += e[m]; }
    #pragma unroll
    for (int m = 0; m < M; ++m) wL[m] = e[m] / s;
  }
  __syncthreads();
  const float w0 = wL[0], w1 = wL[1], w2 = wL[2], w3 = wL[3];
  const float* r0 = rc + (size_t)(b * S1 + n * M + 0) * H;
  const float* r1 = rc + (size_t)(b * S1 + n * M + 1) * H;
  const float* r2 = rc + (size_t)(b * S1 + n * M + 2) * H;
  const float* r3 = rc + (size_t)(b * S1 + n * M + 3) * H;
  #pragma unroll
  for (int k = 0; k < 3; ++k) {
    const int d = t + k * 256;
    pooled[(size_t)bid * H + d] = w0 * r0[d] + w1 * r1[d] + w2 * r2[d] + w3 * r3[d];
  }
}

// ---------------------------------------------------------------------------
// K5: y = pooled @ W_t^T + b_t.  Grid 128 = (b*8 + hc), 1024 threads.
// R18: bid%8 == hc, so (assuming round-robin block->XCD) all 16 b-blocks
// sharing W_t's 96-row tile land on ONE XCD -> W_t fetched 2.25MB total
// (no 8x duplication), while 128 blocks keep the device busy.
// Register-light r-outer loop (~60 VGPR) so all 16 waves fit.
// ---------------------------------------------------------------------------
__global__ __launch_bounds__(1024)
void k_transform(const float* __restrict__ pooled, const float* __restrict__ W_t,
                 const float* __restrict__ b_t, float* __restrict__ yb) {
  const int bid = blockIdx.x, t = threadIdx.x;
  const int b = bid >> 3, hc = bid & 7;   // bid%8 == hc -> XCD-exclusive W_t tile
  const int lane = t & 63, w = t >> 6;    // 16 waves; wave owns rows h = hc*96 + w*6 + r
  __shared__ float pL[NS * H];            // 24.6 KiB pooled[b]
  {
    float4* d4 = (float4*)pL;
    const float4* s4 = (const float4*)(pooled + (size_t)b * NS * H);
    for (int i = t; i < NS * HV4; i += 1024) d4[i] = s4[i];
  }
  __syncthreads();
  #pragma unroll 1
  for (int r = 0; r < 6; ++r) {
    const int h = hc * 96 + w * 6 + r;
    const float4* wr = (const float4*)(W_t + (size_t)h * H);
    const float4 wv0 = wr[lane];
    const float4 wv1 = wr[lane + 64];
    const float4 wv2 = wr[lane + 128];
    float part[NS];
    #pragma unroll
    for (int n = 0; n < NS; ++n) {
      const float4* pq = (const float4*)(pL + n * H);
      const float4 p0 = pq[lane];
      const float4 p1 = pq[lane + 64];
      const float4 p2 = pq[lane + 128];
      part[n] = wv0.x * p0.x + wv0.y * p0.y + wv0.z * p0.z + wv0.w * p0.w
              + wv1.x * p1.x + wv1.y * p1.y + wv1.z * p1.z + wv1.w * p1.w
              + wv2.x * p2.x + wv2.y * p2.y + wv2.z * p2.z + wv2.w * p2.w;
    }
    #pragma unroll
    for (int off = 32; off > 0; off >>= 1) {
      #pragma unroll
      for (int n = 0; n < NS; ++n) part[n] += __shfl_down(part[n], off);
    }
    if (lane == 0) {
      const float bias = b_t[h];
      #pragma unroll
      for (int n = 0; n < NS; ++n)
        yb[((size_t)b * NS + n) * H + h] = part[n] + bias;
    }
  }
}

// ---------------------------------------------------------------------------
// K6: fused row-LayerNorm + cosine score. [R13-identical]
// ---------------------------------------------------------------------------
__global__ __launch_bounds__(256)
void k_lnscore(const float* __restrict__ yb, const float* __restrict__ gamma,
               const float* __restrict__ beta, const float* __restrict__ sel_ln,
               float* __restrict__ out) {
  const int b = blockIdx.x, t = threadIdx.x;
  const int lane = t & 63, w = t >> 6;
  __shared__ float redS[NS * 4];
  __shared__ float redQ[NS * 4];
  float v[NS][3];
  for (int n = 0; n < NS; ++n) {
    float s = 0.f, ss = 0.f;
    #pragma unroll
    for (int k = 0; k < 3; ++k) {
      const float x = yb[((size_t)b * NS + n) * H + t + k * 256];
      v[n][k] = x; s += x; ss += x * x;
    }
    #pragma unroll
    for (int off = 32; off > 0; off >>= 1) {
      s += __shfl_down(s, off);
      ss += __shfl_down(ss, off);
    }
    if (lane == 0) { redS[n * 4 + w] = s; redQ[n * 4 + w] = ss; }
  }
  __syncthreads();
  float g[3], be[3];
  #pragma unroll
  for (int k = 0; k < 3; ++k) { g[k] = gamma[t + k * 256]; be[k] = beta[t + k * 256]; }
  float S[3] = {0.f, 0.f, 0.f}, SS[3] = {0.f, 0.f, 0.f};
  for (int n = 0; n < NS; ++n) {
    const float Sn = redS[n * 4] + redS[n * 4 + 1] + redS[n * 4 + 2] + redS[n * 4 + 3];
    const float Qn = redQ[n * 4] + redQ[n * 4 + 1] + redQ[n * 4 + 2] + redQ[n * 4 + 3];
    const float mu = Sn / (float)H;
    const float var = Qn / (float)H - mu * mu;
    const float rstd = rsqrtf(var + 1e-12f);
    #pragma unroll
    for (int k = 0; k < 3; ++k) {
      const float c = (v[n][k] - mu) * rstd * g[k] + be[k];
      S[k] += c; SS[k] += c * c;
    }
  }
  #pragma unroll
  for (int k = 0; k < 3; ++k) {
    const int h = t + k * 256;
    const float sl = sel_ln[(size_t)b * H + h];
    const float n1 = 2.8284271247461903f * fabsf(sl);  // sqrt(8)*|sel|
    const float n2 = sqrtf(SS[k]);
    out[(size_t)b * H + h] = sl * S[k] / (fmaxf(n1, 1e-8f) * fmaxf(n2, 1e-8f));
  }
}

// ---------------------------------------------------------------------------
extern "C" void kernel_launch(void* const* d_in, const int* in_sizes, int n_in,
                              void* d_out, int out_size, void* d_ws, size_t ws_size,
                              hipStream_t stream) {
  const float* hidden_states = (const float*)d_in[0];
  const float* sent_h1       = (const float*)d_in[1];
  const float* sent_h2       = (const float*)d_in[2];
  const int*   attention_mask= (const int*)  d_in[3];
  const float* expl_h1       = (const float*)d_in[4];
  const float* expl_h2       = (const float*)d_in[5];
  const int*   extra_am      = (const int*)  d_in[6];
  const int*   extra_index   = (const int*)  d_in[7];
  const int*   extra_start   = (const int*)  d_in[8];
  const int*   extra_end     = (const int*)  d_in[9];
  const float* W_attn        = (const float*)d_in[10];
  const float* W_t           = (const float*)d_in[11];
  const float* b_t           = (const float*)d_in[12];
  const float* gamma_t       = (const float*)d_in[13];
  const float* beta_t        = (const float*)d_in[14];
  const float* gamma_s       = (const float*)d_in[15];
  const float* beta_s        = (const float*)d_in[16];
  float* out = (float*)d_out;

  float* ws = (float*)d_ws;
  float* row_cls  = ws;                        // 512*768
  float* sp_part  = row_cls + 512 * H;         // 512*768
  float* sp_cnt   = sp_part + 512 * H;         // 512
  float* sel_part = sp_cnt + 512;              // 512*768
  float* sel_cnt  = sel_part + 512 * H;        // 512
  float* sel_ln   = sel_cnt + 512;             // 16*768
  float* sp       = sel_ln + B * H;            // 16*768
  float* simp     = sp + B * H;                // 16*12*32
  float* pooled   = simp + B * 12 * S1;        // 128*768
  float* yb       = pooled + B * NS * H;       // 128*768

  k_pool<<<1536, 384, 0, stream>>>(expl_h1, expl_h2, extra_am,
                                   sent_h1, sent_h2, attention_mask,
                                   hidden_states, extra_start, extra_end,
                                   row_cls, sp_part, sp_cnt, sel_part, sel_cnt);
  k_sp<<<32, 256, 0, stream>>>(sp_part, sp_cnt, sel_part, sel_cnt,
                               gamma_s, beta_s, sp, sel_ln);
  k_mid_q<<<192, 1024, 0, stream>>>(sp, W_attn, row_cls, simp);
  k_attn_pool<<<128, 256, 0, stream>>>(simp, row_cls, extra_index, pooled);
  k_transform<<<128, 1024, 0, stream>>>(pooled, W_t, b_t, yb);
  k_lnscore<<<B, 256, 0, stream>>>(yb, gamma_t, beta_t, sel_ln, out);
}

// Round 19
// 73.210 us; speedup vs baseline: 3.7547x; 1.0989x over previous
//
#include <hip/hip_runtime.h>
#include <math.h>

// Problem constants (fixed by setup_inputs)
#define B   16
#define L   512
#define H   768
#define HV4 192      // H/4 float4s per row
#define S1  32
#define S2  128
#define NS  8
#define M   4
#define CH  16       // L-chunk rows per partial block
#define NCHUNK 32    // L / CH

// ---------------------------------------------------------------------------
// K1 (fused): 1536 blocks, 384 threads. [R13-identical]
// ---------------------------------------------------------------------------
__global__ __launch_bounds__(384)
void k_pool(const float* __restrict__ e1, const float* __restrict__ e2,
            const int* __restrict__ am,
            const float* __restrict__ s1, const float* __restrict__ s2,
            const int* __restrict__ iam,
            const float* __restrict__ hs, const int* __restrict__ st_,
            const int* __restrict__ en_,
            float* __restrict__ row_cls,
            float* __restrict__ sp_part, float* __restrict__ sp_cnt,
            float* __restrict__ sel_part, float* __restrict__ sel_cnt) {
  const int bid = blockIdx.x;
  const int t = threadIdx.x;
  const int half = t / 192;       // wave-uniform (waves 0-2 vs 3-5)
  const int tt = t % 192;
  __shared__ int   idxL[S2];
  __shared__ int   cntS;
  __shared__ float4 pf[192];      // half-1 partials for the combine

  if (bid < 512) {
    const int i = bid;
    if (t < 64) {
      const int m0 = am[i * S2 + t];
      const int m1 = am[i * S2 + 64 + t];
      const unsigned long long b0 = __ballot(m0 != 0);
      const unsigned long long b1 = __ballot(m1 != 0);
      const int c0 = (int)__popcll(b0);
      if (m0) idxL[(int)__popcll(b0 & ((1ULL << t) - 1))] = t;
      if (m1) idxL[c0 + (int)__popcll(b1 & ((1ULL << t) - 1))] = 64 + t;
      if (t == 0) cntS = c0 + (int)__popcll(b1);
    }
    __syncthreads();
    const int cnt = cntS;
    const int cntH = (cnt + 1 - half) >> 1;   // half0 ceil, half1 floor
    const float4* p1 = (const float4*)e1 + (size_t)i * (S2 * HV4) + tt;
    const float4* p2 = (const float4*)e2 + (size_t)i * (S2 * HV4) + tt;
    float ax = 0.f, ay = 0.f, az = 0.f, aw = 0.f;
    int kk = 0;
    for (; kk + 3 < cntH; kk += 4) {
      const int j0 = idxL[2 * kk + half];
      const int j1 = idxL[2 * (kk + 1) + half];
      const int j2 = idxL[2 * (kk + 2) + half];
      const int j3 = idxL[2 * (kk + 3) + half];
      float4 a0 = p1[j0 * HV4], b0 = p2[j0 * HV4];
      float4 a1 = p1[j1 * HV4], b1 = p2[j1 * HV4];
      float4 a2 = p1[j2 * HV4], b2 = p2[j2 * HV4];
      float4 a3 = p1[j3 * HV4], b3 = p2[j3 * HV4];
      ax += (a0.x + b0.x) + (a1.x + b1.x) + (a2.x + b2.x) + (a3.x + b3.x);
      ay += (a0.y + b0.y) + (a1.y + b1.y) + (a2.y + b2.y) + (a3.y + b3.y);
      az += (a0.z + b0.z) + (a1.z + b1.z) + (a2.z + b2.z) + (a3.z + b3.z);
      aw += (a0.w + b0.w) + (a1.w + b1.w) + (a2.w + b2.w) + (a3.w + b3.w);
    }
    for (; kk < cntH; ++kk) {
      const int j = idxL[2 * kk + half];
      float4 a = p1[j * HV4], b = p2[j * HV4];
      ax += a.x + b.x; ay += a.y + b.y; az += a.z + b.z; aw += a.w + b.w;
    }
    if (half == 1) { float4 o; o.x = ax; o.y = ay; o.z = az; o.w = aw; pf[tt] = o; }
    __syncthreads();
    if (half == 0) {
      const float inv = 1.f / (float)cnt;
      float4 o = pf[tt];
      o.x = (ax + o.x) * inv; o.y = (ay + o.y) * inv;
      o.z = (az + o.z) * inv; o.w = (aw + o.w) * inv;
      ((float4*)row_cls)[(size_t)i * HV4 + tt] = o;
    }
  } else if (bid < 1024) {
    const int blk = bid - 512;
    const int b = blk >> 5, c = blk & 31;
    if (t < 64) {
      const int m = (t < CH) ? iam[b * L + c * CH + t] : 0;
      const unsigned long long bm = __ballot(m != 0);
      if (m) idxL[(int)__popcll(bm & ((1ULL << t) - 1))] = t;
      if (t == 0) { const int cc = (int)__popcll(bm); cntS = cc; sp_cnt[blk] = (float)cc; }
    }
    __syncthreads();
    const int cnt = cntS;
    const int cntH = (cnt + 1 - half) >> 1;
    const float4* p1 = (const float4*)s1 + ((size_t)b * L + c * CH) * HV4 + tt;
    const float4* p2 = (const float4*)s2 + ((size_t)b * L + c * CH) * HV4 + tt;
    float ax = 0.f, ay = 0.f, az = 0.f, aw = 0.f;
    int kk = 0;
    for (; kk + 1 < cntH; kk += 2) {
      const int l0 = idxL[2 * kk + half];
      const int l1 = idxL[2 * (kk + 1) + half];
      float4 a0 = p1[l0 * HV4], b0 = p2[l0 * HV4];
      float4 a1 = p1[l1 * HV4], b1 = p2[l1 * HV4];
      ax += (a0.x + b0.x) + (a1.x + b1.x);
      ay += (a0.y + b0.y) + (a1.y + b1.y);
      az += (a0.z + b0.z) + (a1.z + b1.z);
      aw += (a0.w + b0.w) + (a1.w + b1.w);
    }
    for (; kk < cntH; ++kk) {
      const int l = idxL[2 * kk + half];
      float4 a = p1[l * HV4], b = p2[l * HV4];
      ax += a.x + b.x; ay += a.y + b.y; az += a.z + b.z; aw += a.w + b.w;
    }
    if (half == 1) { float4 o; o.x = ax; o.y = ay; o.z = az; o.w = aw; pf[tt] = o; }
    __syncthreads();
    if (half == 0) {
      float4 o = pf[tt];
      o.x += ax; o.y += ay; o.z += az; o.w += aw;
      ((float4*)sp_part)[(size_t)blk * HV4 + tt] = o;
    }
  } else {
    const int blk = bid - 1024;
    const int b = blk >> 5, c = blk & 31;
    const int st = st_[b], en = en_[b];
    const int lo = st > c * CH ? st : c * CH;
    const int hi = en < c * CH + CH ? en : c * CH + CH;
    const float4* p = (const float4*)hs + (size_t)b * L * HV4 + tt;
    float ax = 0.f, ay = 0.f, az = 0.f, aw = 0.f;
    for (int l = lo + half; l < hi; l += 2) {   // this half's rows, in-bounds
      float4 a0 = p[l * HV4];
      ax += a0.x; ay += a0.y; az += a0.z; aw += a0.w;
    }
    if (half == 1) { float4 o; o.x = ax; o.y = ay; o.z = az; o.w = aw; pf[tt] = o; }
    __syncthreads();
    if (half == 0) {
      float4 o = pf[tt];
      o.x += ax; o.y += ay; o.z += az; o.w += aw;
      ((float4*)sel_part)[(size_t)blk * HV4 + tt] = o;
      if (tt == 0) sel_cnt[blk] = (float)(hi > lo ? hi - lo : 0);
    }
  }
}

// ---------------------------------------------------------------------------
// K2: combines. Grid 32 blocks, 256 threads. [R13-identical]
// ---------------------------------------------------------------------------
__global__ __launch_bounds__(256)
void k_sp(const float* __restrict__ sp_part, const float* __restrict__ sp_cnt,
          const float* __restrict__ sel_part, const float* __restrict__ sel_cnt,
          const float* __restrict__ gamma_s, const float* __restrict__ beta_s,
          float* __restrict__ sp, float* __restrict__ sel_ln) {
  const int bid = blockIdx.x, t = threadIdx.x;
  const int lane = t & 63, w = t >> 6;
  __shared__ float red[8];
  if (bid < B) {
    const int b = bid;
    float csp = 0.f;
    for (int c = 0; c < NCHUNK; ++c) csp += sp_cnt[b * NCHUNK + c];
    const float inv = 1.f / csp;
    #pragma unroll
    for (int k = 0; k < 3; ++k) {
      const int h = t + k * 256;
      float a = 0.f;
      #pragma unroll
      for (int c = 0; c < NCHUNK; ++c)
        a += sp_part[((size_t)b * NCHUNK + c) * H + h];
      sp[(size_t)b * H + h] = a * inv;
    }
  } else {
    const int b = bid - B;
    float csel = 0.f;
    for (int c = 0; c < NCHUNK; ++c) csel += sel_cnt[b * NCHUNK + c];
    const float invc = 1.f / csel;
    float selv[3];
    #pragma unroll
    for (int k = 0; k < 3; ++k) {
      const int h = t + k * 256;
      float s = 0.f;
      #pragma unroll
      for (int c = 0; c < NCHUNK; ++c)
        s += sel_part[((size_t)b * NCHUNK + c) * H + h];
      selv[k] = s * invc;
    }
    float s = selv[0] + selv[1] + selv[2];
    float ss = selv[0] * selv[0] + selv[1] * selv[1] + selv[2] * selv[2];
    #pragma unroll
    for (int off = 32; off > 0; off >>= 1) {
      s += __shfl_down(s, off);
      ss += __shfl_down(ss, off);
    }
    if (lane == 0) { red[w] = s; red[4 + w] = ss; }
    __syncthreads();
    const float S = red[0] + red[1] + red[2] + red[3];
    const float SS = red[4] + red[5] + red[6] + red[7];
    const float mu = S / (float)H;
    const float var = SS / (float)H - mu * mu;
    const float rstd = rsqrtf(var + 1e-12f);
    #pragma unroll
    for (int k = 0; k < 3; ++k) {
      const int h = t + k * 256;
      sel_ln[(size_t)b * H + h] = (selv[k] - mu) * rstd * gamma_s[h] + beta_s[h];
    }
  }
}

// ---------------------------------------------------------------------------
// K3: q-tile + sim partials, 1024 threads. [R13-identical]
// ---------------------------------------------------------------------------
__global__ __launch_bounds__(1024)
void k_mid_q(const float* __restrict__ sp, const float* __restrict__ W_attn,
             const float* __restrict__ rc, float* __restrict__ simp) {
  const int bid = blockIdx.x, t = threadIdx.x;
  const int b = bid / 12, ht = bid % 12;
  const int lane = t & 63, w = t >> 6;     // 16 waves
  __shared__ float spL[H];
  __shared__ float red[1024];
  __shared__ float qt[64];
  if (t < H) spL[t] = sp[(size_t)b * H + t];
  __syncthreads();
  {
    const int h = ht * 64 + lane;
    const float* wp = W_attn + (size_t)(w * 48) * H + h;
    const float* sv = spL + w * 48;
    float acc = 0.f;
    #pragma unroll 8
    for (int i = 0; i < 48; ++i) acc += sv[i] * wp[(size_t)i * H];
    red[t] = acc;
  }
  __syncthreads();
  if (t < 64) {
    float a = 0.f;
    #pragma unroll
    for (int ww = 0; ww < 16; ++ww) a += red[ww * 64 + t];
    qt[t] = a;
  }
  __syncthreads();
  {
    const int i = t >> 5, sub = t & 31;
    const float* rr = rc + (size_t)(b * S1 + i) * H + ht * 64 + sub * 2;
    float p = qt[sub * 2] * rr[0] + qt[sub * 2 + 1] * rr[1];
    p += __shfl_down(p, 16);
    p += __shfl_down(p, 8);
    p += __shfl_down(p, 4);
    p += __shfl_down(p, 2);
    p += __shfl_down(p, 1);
    if (sub == 0) simp[((size_t)b * 12 + ht) * S1 + i] = p;
  }
}

// ---------------------------------------------------------------------------
// K4: sims reduce + ragged softmax + pooled materialization.
// Grid 128 (b x n), 256 threads. Each rc row read exactly once globally.
// [R17/R18-validated body]
// ---------------------------------------------------------------------------
__global__ __launch_bounds__(256)
void k_attn_pool(const float* __restrict__ simp, const float* __restrict__ rc,
                 const int* __restrict__ extra_index, float* __restrict__ pooled) {
  const int bid = blockIdx.x, t = threadIdx.x;
  const int b = bid >> 3, n = bid & 7;
  __shared__ float simL[M];
  __shared__ float wL[M];
  if (t < M) {
    float a = 0.f;
    #pragma unroll
    for (int ht = 0; ht < 12; ++ht)
      a += simp[((size_t)b * 12 + ht) * S1 + n * M + t];
    simL[t] = a;
  }
  __syncthreads();
  if (t == 0) {
    const int vid = extra_index[b * NS + n];
    const float scale = 0.036084391824351615f;  // 1/sqrt(768)
    float x[M], mx = -1e30f;
    #pragma unroll
    for (int m = 0; m < M; ++m) {
      x[m] = (m < vid) ? simL[m] * scale : -1e30f;
      mx = fmaxf(mx, x[m]);
    }
    float s = 0.f, e[M];
    #pragma unroll
    for (int m = 0; m < M; ++m) { e[m] = expf(x[m] - mx); s += e[m]; }
    #pragma unroll
    for (int m = 0; m < M; ++m) wL[m] = e[m] / s;
  }
  __syncthreads();
  const float w0 = wL[0], w1 = wL[1], w2 = wL[2], w3 = wL[3];
  const float* r0 = rc + (size_t)(b * S1 + n * M + 0) * H;
  const float* r1 = rc + (size_t)(b * S1 + n * M + 1) * H;
  const float* r2 = rc + (size_t)(b * S1 + n * M + 2) * H;
  const float* r3 = rc + (size_t)(b * S1 + n * M + 3) * H;
  #pragma unroll
  for (int k = 0; k < 3; ++k) {
    const int d = t + k * 256;
    pooled[(size_t)bid * H + d] = w0 * r0[d] + w1 * r1[d] + w2 * r2[d] + w3 * r3[d];
  }
}

// ---------------------------------------------------------------------------
// K5: y-stripe GEMM only. Grid 192 (b x 12 hc), 1024 threads.
// R19: EXACT R13 y-GEMM body (validated at 73.4), but pooled is now READ
// (24KB from L2, 12x dup = 3MB) instead of recomputed from rc (98KB gather,
// 18.9MB global dup) — strictly less work and less traffic than R13's k_attn_tr.
// ---------------------------------------------------------------------------
__global__ __launch_bounds__(1024)
void k_attn_tr(const float* __restrict__ pooled,
               const float* __restrict__ W_t, const float* __restrict__ b_t,
               float* __restrict__ yb) {
  const int bid = blockIdx.x, t = threadIdx.x;
  const int b = bid / 12, hc = bid % 12;
  const int lane = t & 63, w = t >> 6;     // 16 waves
  __shared__ float pL[NS * H];   // 24 KiB pooled
  // stage pooled[b] (8x768 floats = 1536 float4), coalesced
  {
    float4* d4 = (float4*)pL;
    const float4* s4 = (const float4*)(pooled + (size_t)b * NS * H);
    #pragma unroll
    for (int i = t; i < NS * HV4; i += 1024) d4[i] = s4[i];
  }
  __syncthreads();
  // y GEMM (coalesced): wave w -> rows h = hc*64 + w*4 + r  [R13 body]
  #pragma unroll 1
  for (int r = 0; r < 4; ++r) {
    const int h = hc * 64 + w * 4 + r;
    const float4* wr = (const float4*)(W_t + (size_t)h * H);
    const float4 wv0 = wr[lane];
    const float4 wv1 = wr[lane + 64];
    const float4 wv2 = wr[lane + 128];
    float part[NS];
    #pragma unroll
    for (int n = 0; n < NS; ++n) {
      const float4* pq = (const float4*)(pL + n * H);
      const float4 p0 = pq[lane];
      const float4 p1 = pq[lane + 64];
      const float4 p2 = pq[lane + 128];
      part[n] = wv0.x * p0.x + wv0.y * p0.y + wv0.z * p0.z + wv0.w * p0.w
              + wv1.x * p1.x + wv1.y * p1.y + wv1.z * p1.z + wv1.w * p1.w
              + wv2.x * p2.x + wv2.y * p2.y + wv2.z * p2.z + wv2.w * p2.w;
    }
    #pragma unroll
    for (int off = 32; off > 0; off >>= 1) {
      #pragma unroll
      for (int n = 0; n < NS; ++n) part[n] += __shfl_down(part[n], off);
    }
    if (lane == 0) {
      const float bias = b_t[h];
      #pragma unroll
      for (int n = 0; n < NS; ++n)
        yb[((size_t)b * NS + n) * H + h] = part[n] + bias;
    }
  }
}

// ---------------------------------------------------------------------------
// K6: fused row-LayerNorm + cosine score. [R13-identical]
// ---------------------------------------------------------------------------
__global__ __launch_bounds__(256)
void k_lnscore(const float* __restrict__ yb, const float* __restrict__ gamma,
               const float* __restrict__ beta, const float* __restrict__ sel_ln,
               float* __restrict__ out) {
  const int b = blockIdx.x, t = threadIdx.x;
  const int lane = t & 63, w = t >> 6;
  __shared__ float redS[NS * 4];
  __shared__ float redQ[NS * 4];
  float v[NS][3];
  for (int n = 0; n < NS; ++n) {
    float s = 0.f, ss = 0.f;
    #pragma unroll
    for (int k = 0; k < 3; ++k) {
      const float x = yb[((size_t)b * NS + n) * H + t + k * 256];
      v[n][k] = x; s += x; ss += x * x;
    }
    #pragma unroll
    for (int off = 32; off > 0; off >>= 1) {
      s += __shfl_down(s, off);
      ss += __shfl_down(ss, off);
    }
    if (lane == 0) { redS[n * 4 + w] = s; redQ[n * 4 + w] = ss; }
  }
  __syncthreads();
  float g[3], be[3];
  #pragma unroll
  for (int k = 0; k < 3; ++k) { g[k] = gamma[t + k * 256]; be[k] = beta[t + k * 256]; }
  float S[3] = {0.f, 0.f, 0.f}, SS[3] = {0.f, 0.f, 0.f};
  for (int n = 0; n < NS; ++n) {
    const float Sn = redS[n * 4] + redS[n * 4 + 1] + redS[n * 4 + 2] + redS[n * 4 + 3];
    const float Qn = redQ[n * 4] + redQ[n * 4 + 1] + redQ[n * 4 + 2] + redQ[n * 4 + 3];
    const float mu = Sn / (float)H;
    const float var = Qn / (float)H - mu * mu;
    const float rstd = rsqrtf(var + 1e-12f);
    #pragma unroll
    for (int k = 0; k < 3; ++k) {
      const float c = (v[n][k] - mu) * rstd * g[k] + be[k];
      S[k] += c; SS[k] += c * c;
    }
  }
  #pragma unroll
  for (int k = 0; k < 3; ++k) {
    const int h = t + k * 256;
    const float sl = sel_ln[(size_t)b * H + h];
    const float n1 = 2.8284271247461903f * fabsf(sl);  // sqrt(8)*|sel|
    const float n2 = sqrtf(SS[k]);
    out[(size_t)b * H + h] = sl * S[k] / (fmaxf(n1, 1e-8f) * fmaxf(n2, 1e-8f));
  }
}

// ---------------------------------------------------------------------------
extern "C" void kernel_launch(void* const* d_in, const int* in_sizes, int n_in,
                              void* d_out, int out_size, void* d_ws, size_t ws_size,
                              hipStream_t stream) {
  const float* hidden_states = (const float*)d_in[0];
  const float* sent_h1       = (const float*)d_in[1];
  const float* sent_h2       = (const float*)d_in[2];
  const int*   attention_mask= (const int*)  d_in[3];
  const float* expl_h1       = (const float*)d_in[4];
  const float* expl_h2       = (const float*)d_in[5];
  const int*   extra_am      = (const int*)  d_in[6];
  const int*   extra_index   = (const int*)  d_in[7];
  const int*   extra_start   = (const int*)  d_in[8];
  const int*   extra_end     = (const int*)  d_in[9];
  const float* W_attn        = (const float*)d_in[10];
  const float* W_t           = (const float*)d_in[11];
  const float* b_t           = (const float*)d_in[12];
  const float* gamma_t       = (const float*)d_in[13];
  const float* beta_t        = (const float*)d_in[14];
  const float* gamma_s       = (const float*)d_in[15];
  const float* beta_s        = (const float*)d_in[16];
  float* out = (float*)d_out;

  float* ws = (float*)d_ws;
  float* row_cls  = ws;                        // 512*768
  float* sp_part  = row_cls + 512 * H;         // 512*768
  float* sp_cnt   = sp_part + 512 * H;         // 512
  float* sel_part = sp_cnt + 512;              // 512*768
  float* sel_cnt  = sel_part + 512 * H;        // 512
  float* sel_ln   = sel_cnt + 512;             // 16*768
  float* sp       = sel_ln + B * H;            // 16*768
  float* simp     = sp + B * H;                // 16*12*32
  float* pooled   = simp + B * 12 * S1;        // 128*768
  float* yb       = pooled + B * NS * H;       // 128*768

  k_pool<<<1536, 384, 0, stream>>>(expl_h1, expl_h2, extra_am,
                                   sent_h1, sent_h2, attention_mask,
                                   hidden_states, extra_start, extra_end,
                                   row_cls, sp_part, sp_cnt, sel_part, sel_cnt);
  k_sp<<<32, 256, 0, stream>>>(sp_part, sp_cnt, sel_part, sel_cnt,
                               gamma_s, beta_s, sp, sel_ln);
  k_mid_q<<<192, 1024, 0, stream>>>(sp, W_attn, row_cls, simp);
  k_attn_pool<<<128, 256, 0, stream>>>(simp, row_cls, extra_index, pooled);
  k_attn_tr<<<192, 1024, 0, stream>>>(pooled, W_t, b_t, yb);
  k_lnscore<<<B, 256, 0, stream>>>(yb, gamma_t, beta_t, sel_ln, out);
}